// Round 1
// 854.359 us; speedup vs baseline: 1.0316x; 1.0316x over previous
//
#include <hip/hip_runtime.h>

// DynamicUpsamplingFilter: per-pixel (3x25)@(25x16) matmul.
// x:      (1, 3, 25, 128, 128)  fp32
// filters:(1, 25, 16, 25, 128, 128) fp32   (k, u, t, h, w) after squeezing n
// out:    (1, 48, 25, 128, 128) fp32, out[c*16+u] = sum_k patch[c][k]*filt[k][u]
//
// Memory-bound: filters 655MB read-once + out 78.6MB write-once dominate.
// v2: float4-wide everything. Each thread = 4 consecutive pixels x 4 u's x 3 c.
//   - block = 256 threads = 4 waves; wave uq handles u in [4*uq, 4*uq+4)
//   - lane l covers pixels P0 + 4*l .. +3  -> filter loads are dwordx4,
//     64 lanes x 16B = 1KB contiguous per instruction (coalescing sweet spot)
//   - x halo staged in LDS (zero-padded), read back as aligned ds_read_b128;
//     no bounds checks in the hot loop.
//   - every filter byte still read exactly once (u split across waves).

#define T_ 25
#define H_ 128
#define W_ 128
#define C_ 3
#define U_ 16
#define KH_ 5
#define KW_ 5
#define HW_ (H_ * W_)       // 16384
#define THW_ (T_ * HW_)     // 409600

#define BLOCK_PIX 256       // pixels per block (= 2 full image rows)
#define LROWS 6             // h0-2 .. h0+3
#define LCOLS 132           // -2 .. 129 (zero-padded halo)

__global__ __launch_bounds__(256) void duf_kernel(
    const float* __restrict__ x,     // (3, 25, 128, 128)
    const float* __restrict__ filt,  // (25, 16, 25, 128, 128)
    float* __restrict__ out)         // (48, 25, 128, 128)
{
    __shared__ __align__(16) float xs[C_ * LROWS * LCOLS];  // 9504 B

    const int tid = threadIdx.x;
    const int P0  = blockIdx.x * BLOCK_PIX;      // block's first pixel
    const int t   = P0 / HW_;                    // whole block in one t
    const int h0  = (P0 - t * HW_) / W_;         // rows h0, h0+1 (full rows)

    // ---- cooperative x staging: rows h0-2..h0+3, cols -2..129, zero-padded
    const float* xt = x + (size_t)t * HW_;
    for (int idx = tid; idx < C_ * LROWS * LCOLS; idx += 256) {
        const int c   = idx / (LROWS * LCOLS);
        const int rem = idx - c * (LROWS * LCOLS);
        const int r   = rem / LCOLS;
        const int col = rem - r * LCOLS;
        const int gh  = h0 - 2 + r;
        const int gw  = col - 2;
        float v = 0.f;
        if ((unsigned)gh < (unsigned)H_ && (unsigned)gw < (unsigned)W_)
            v = xt[(size_t)c * THW_ + gh * W_ + gw];
        xs[idx] = v;
    }
    __syncthreads();

    const int lane = tid & 63;
    const int uq   = tid >> 6;             // 0..3: this wave's u-quad
    const int p0   = P0 + lane * 4;        // first of 4 pixels for this thread
    const int lrow = lane >> 5;            // 0/1: which of the block's 2 rows
    const int w0   = (lane & 31) * 4;      // pixel column base, multiple of 4

    float4 acc[C_][4];
#pragma unroll
    for (int c = 0; c < C_; ++c)
#pragma unroll
        for (int u = 0; u < 4; ++u)
            acc[c][u] = make_float4(0.f, 0.f, 0.f, 0.f);

    // filter base for this wave's u-quad and this thread's pixel quad
    const float* fb = filt + (size_t)(uq * 4) * THW_ + p0;

#pragma unroll 1
    for (int a = 0; a < KH_; ++a) {
        // 8 x-columns needed per c: lds cols w0 .. w0+7 (aligned 16B)
        float xr[C_][8];
#pragma unroll
        for (int c = 0; c < C_; ++c) {
            const float4* s =
                (const float4*)&xs[(c * LROWS + lrow + a) * LCOLS + w0];
            const float4 lo = s[0];
            const float4 hi = s[1];
            xr[c][0] = lo.x; xr[c][1] = lo.y; xr[c][2] = lo.z; xr[c][3] = lo.w;
            xr[c][4] = hi.x; xr[c][5] = hi.y; xr[c][6] = hi.z; xr[c][7] = hi.w;
        }
        const float* fa = fb + (size_t)a * (KW_ * U_) * THW_;
#pragma unroll
        for (int b = 0; b < KW_; ++b) {
#pragma unroll
            for (int u = 0; u < 4; ++u) {
                const float4 f =
                    *(const float4*)(fa + (size_t)(b * U_ + u) * THW_);
#pragma unroll
                for (int c = 0; c < C_; ++c) {
                    acc[c][u].x += xr[c][b + 0] * f.x;
                    acc[c][u].y += xr[c][b + 1] * f.y;
                    acc[c][u].z += xr[c][b + 2] * f.z;
                    acc[c][u].w += xr[c][b + 3] * f.w;
                }
            }
        }
    }

#pragma unroll
    for (int c = 0; c < C_; ++c)
#pragma unroll
        for (int u = 0; u < 4; ++u)
            *(float4*)(out + (size_t)(c * U_ + uq * 4 + u) * THW_ + p0) =
                acc[c][u];
}

extern "C" void kernel_launch(void* const* d_in, const int* in_sizes, int n_in,
                              void* d_out, int out_size, void* d_ws, size_t ws_size,
                              hipStream_t stream) {
    const float* x = (const float*)d_in[0];
    const float* filt = (const float*)d_in[1];
    float* out = (float*)d_out;
    dim3 grid(THW_ / BLOCK_PIX);  // 1600 blocks, exact
    dim3 block(256);
    duf_kernel<<<grid, block, 0, stream>>>(x, filt, out);
}

// Round 3
// 852.218 us; speedup vs baseline: 1.0342x; 1.0025x over previous
//
#include <hip/hip_runtime.h>

// DynamicUpsamplingFilter: per-pixel (3x25)@(25x16) matmul.
// x:      (1, 3, 25, 128, 128)  fp32
// filters:(1, 25, 16, 25, 128, 128) fp32   (k, u, t, h, w)
// out:    (1, 48, 25, 128, 128) fp32, out[c*16+u] = sum_k patch[c][k]*filt[k][u]
//
// v3b: long-stream restructure (v3 with clang-native vec4 for nontemporal).
//   - wave owns ONE u and a 16-row pixel span (2048 px)
//   - thread owns 8 pixel-quads (32 px, interleaved j*256 + lane*4)
//   - for fixed k: 8 x dwordx4 wave-loads = 8KB CONTIGUOUS per stream
//     (v2 read 1KB granules from 20 streams -> DRAM/stream confetti)
//   - block = 4 waves = 4 consecutive u's sharing one x LDS tile
//   - stores: 8KB contiguous per (c,u) stream, nontemporal
// Every filter byte still read exactly once.

typedef float f4 __attribute__((ext_vector_type(4)));

#define T_ 25
#define H_ 128
#define W_ 128
#define C_ 3
#define U_ 16
#define KH_ 5
#define KW_ 5
#define HW_ (H_ * W_)       // 16384
#define THW_ (T_ * HW_)     // 409600

#define SPAN_ROWS 16
#define SPAN_PX (SPAN_ROWS * W_)    // 2048
#define NSPAN (H_ / SPAN_ROWS)      // 8
#define LROWS (SPAN_ROWS + KH_ - 1) // 20 rows: span-2 .. span+17
#define LCOLS (W_ + 4)              // 132: cols -2 .. 129, zero-padded

__global__ __launch_bounds__(256) void duf_kernel(
    const float* __restrict__ x,     // (3, 25, 128, 128)
    const float* __restrict__ filt,  // (25, 16, 25, 128, 128)
    float* __restrict__ out)         // (48, 25, 128, 128)
{
    __shared__ __align__(16) float xs[C_ * LROWS * LCOLS];  // 31680 B

    const int bid = blockIdx.x;
    const int ug  = bid & 3;                 // u-group (fastest: L2 locality on x)
    const int sp  = (bid >> 2) & (NSPAN - 1);
    const int t   = bid >> 5;                // 0..24

    const int tid = threadIdx.x;

    // ---- cooperative x staging: rows sp*16-2 .. sp*16+17, cols -2..129
    const float* xt = x + (size_t)t * HW_;
    for (int idx = tid; idx < C_ * LROWS * LCOLS; idx += 256) {
        const int c   = idx / (LROWS * LCOLS);
        const int rem = idx - c * (LROWS * LCOLS);
        const int r   = rem / LCOLS;
        const int col = rem - r * LCOLS;
        const int gh  = sp * SPAN_ROWS - 2 + r;
        const int gw  = col - 2;
        float v = 0.f;
        if ((unsigned)gh < (unsigned)H_ && (unsigned)gw < (unsigned)W_)
            v = xt[(size_t)c * THW_ + gh * W_ + gw];
        xs[idx] = v;
    }
    __syncthreads();

    const int lane = tid & 63;
    const int wq   = tid >> 6;           // 0..3
    const int u    = ug * 4 + wq;        // this wave's u
    const int lrow = lane >> 5;          // 0/1 within a 2-row j-group
    const int w0   = (lane & 31) * 4;    // column base (16B aligned)

    f4 acc[C_][8];
#pragma unroll
    for (int c = 0; c < C_; ++c)
#pragma unroll
        for (int j = 0; j < 8; ++j)
            acc[c][j] = (f4)(0.f);

    // pixel base for this thread: t, span sp, j-group j covers px j*256+lane*4
    const size_t pixbase = (size_t)t * HW_ + (size_t)sp * SPAN_PX + lane * 4;
    const float* fu = filt + (size_t)u * THW_ + pixbase;

#pragma unroll 1
    for (int a = 0; a < KH_; ++a) {
        const float* fa = fu + (size_t)(a * KW_) * U_ * THW_;
#pragma unroll
        for (int j = 0; j < 8; ++j) {
            // x window: row 2j+lrow+a of the LDS tile, cols w0..w0+7
            float xr[C_][8];
#pragma unroll
            for (int c = 0; c < C_; ++c) {
                const f4* s = (const f4*)
                    &xs[(c * LROWS + 2 * j + lrow + a) * LCOLS + w0];
                const f4 lo = s[0];
                const f4 hi = s[1];
                xr[c][0] = lo.x; xr[c][1] = lo.y; xr[c][2] = lo.z; xr[c][3] = lo.w;
                xr[c][4] = hi.x; xr[c][5] = hi.y; xr[c][6] = hi.z; xr[c][7] = hi.w;
            }
#pragma unroll
            for (int b = 0; b < KW_; ++b) {
                const f4 f = __builtin_nontemporal_load(
                    (const f4*)(fa + (size_t)(b * U_) * THW_ + j * 256));
#pragma unroll
                for (int c = 0; c < C_; ++c) {
                    acc[c][j].x += xr[c][b + 0] * f.x;
                    acc[c][j].y += xr[c][b + 1] * f.y;
                    acc[c][j].z += xr[c][b + 2] * f.z;
                    acc[c][j].w += xr[c][b + 3] * f.w;
                }
            }
        }
    }

    // ---- stores: per (c,u) stream, 8KB contiguous
#pragma unroll
    for (int c = 0; c < C_; ++c) {
        float* oc = out + (size_t)(c * U_ + u) * THW_ + pixbase;
#pragma unroll
        for (int j = 0; j < 8; ++j)
            __builtin_nontemporal_store(acc[c][j], (f4*)(oc + j * 256));
    }
}

extern "C" void kernel_launch(void* const* d_in, const int* in_sizes, int n_in,
                              void* d_out, int out_size, void* d_ws, size_t ws_size,
                              hipStream_t stream) {
    const float* x = (const float*)d_in[0];
    const float* filt = (const float*)d_in[1];
    float* out = (float*)d_out;
    dim3 grid(T_ * NSPAN * 4);  // 25 * 8 * 4 = 800 blocks
    dim3 block(256);
    duf_kernel<<<grid, block, 0, stream>>>(x, filt, out);
}